// Round 3
// baseline (4040.303 us; speedup 1.0000x reference)
//
#include <hip/hip_runtime.h>
#include <stdint.h>

// Problem constants
#define B_ 32
#define T_ 2048
#define D_ 512
#define N_ 512
#define NG 2048   // 4 gates * N

typedef _Float16 f16;
typedef _Float16 half2v __attribute__((ext_vector_type(2)));
typedef _Float16 half8  __attribute__((ext_vector_type(8)));
typedef float    float4v __attribute__((ext_vector_type(4)));
typedef unsigned long long u64;

union U32H2 { unsigned u; half2v h; };
union U4H8  { uint4 u; half8 h; };
union H16U  { f16 h; unsigned short s; };

// ---------------- prep: cast x (f32) -> f16 ----------------
__global__ void prep_cast(const float* __restrict__ x, f16* __restrict__ x16) {
    long i = ((long)blockIdx.x * 256 + threadIdx.x) * 4;
    float4 v = *(const float4*)(x + i);
    union { f16 h[4]; uint2 u; } pk;
    pk.h[0] = (f16)v.x; pk.h[1] = (f16)v.y; pk.h[2] = (f16)v.z; pk.h[3] = (f16)v.w;
    *(uint2*)(x16 + i) = pk.u;
}

// ---------------- prep: transpose+cast weights, biases ----------------
__global__ void prep_w(const float* __restrict__ Wi, const float* __restrict__ Ui,
                       const float* __restrict__ Wf, const float* __restrict__ Uf,
                       const float* __restrict__ Wg, const float* __restrict__ Ug,
                       const float* __restrict__ Wc, const float* __restrict__ Uc,
                       const float* __restrict__ Wo,
                       const float* __restrict__ bi, const float* __restrict__ bff,
                       const float* __restrict__ bg, const float* __restrict__ bc,
                       f16* __restrict__ wt, f16* __restrict__ ut,
                       f16* __restrict__ wot, float* __restrict__ bias)
{
    const int y = blockIdx.y;
    const int e = blockIdx.x * 256 + threadIdx.x;   // 0..262143
    if (y < 4) {
        const float* src = (y == 0) ? Wi : (y == 1) ? Wf : (y == 2) ? Wg : Wc;
        int col = e >> 9, d = e & 511;
        wt[(long)y * 512 * 512 + e] = (f16)src[(long)d * 512 + col];   // wt[(g*512+col)][d]
    } else if (y < 8) {
        const float* src = (y == 4) ? Ui : (y == 5) ? Uf : (y == 6) ? Ug : Uc;
        int col = e >> 9, d = e & 511;
        ut[(long)(y - 4) * 512 * 512 + e] = (f16)src[(long)d * 512 + col];
    } else if (y == 8) {
        int col = e >> 9, d = e & 511;
        wot[e] = (f16)Wo[(long)d * 512 + col];
    } else {
        if (e < 2048) {
            const float* bsrc = (e < 512) ? bi : (e < 1024) ? bff : (e < 1536) ? bg : bc;
            bias[e] = bsrc[e & 511];
        }
    }
}

// ---------------- phase 1: xpre[b][t][2048] = x @ [Wi|Wf|Wg|Wc] + bias (f16 out) ----------------
__launch_bounds__(256)
__global__ void gemm_xw(const f16* __restrict__ A, const f16* __restrict__ Bt,
                        const float* __restrict__ bias, f16* __restrict__ C)
{
    __shared__ f16 sA[128 * 32];
    __shared__ f16 sB[128 * 32];
    const int tid = threadIdx.x;
    const int m0 = blockIdx.y * 128;
    const int n0 = blockIdx.x * 128;
    const int wave = tid >> 6, lane = tid & 63;
    const int wm = wave >> 1, wn = wave & 1;
    const int lrow = lane & 15, quad = lane >> 4;

    float4v acc[4][4];
#pragma unroll
    for (int i = 0; i < 4; i++)
#pragma unroll
        for (int j = 0; j < 4; j++) acc[i][j] = (float4v){0.f, 0.f, 0.f, 0.f};

    const int srow = tid >> 2;        // 0..63
    const int sk8 = (tid & 3) * 8;    // 0,8,16,24

    for (int k0 = 0; k0 < 512; k0 += 32) {
#pragma unroll
        for (int rr = 0; rr < 128; rr += 64) {
            const int row = rr + srow;
            *(uint4*)&sA[row * 32 + sk8] = *(const uint4*)&A[(long)(m0 + row) * 512 + k0 + sk8];
            *(uint4*)&sB[row * 32 + sk8] = *(const uint4*)&Bt[(long)(n0 + row) * 512 + k0 + sk8];
        }
        __syncthreads();
        half8 af[4], bf[4];
#pragma unroll
        for (int mi = 0; mi < 4; mi++)
            af[mi] = *(half8*)&sA[(wm * 64 + mi * 16 + lrow) * 32 + quad * 8];
#pragma unroll
        for (int ni = 0; ni < 4; ni++)
            bf[ni] = *(half8*)&sB[(wn * 64 + ni * 16 + lrow) * 32 + quad * 8];
#pragma unroll
        for (int mi = 0; mi < 4; mi++)
#pragma unroll
            for (int ni = 0; ni < 4; ni++)
                acc[mi][ni] = __builtin_amdgcn_mfma_f32_16x16x32_f16(af[mi], bf[ni], acc[mi][ni], 0, 0, 0);
        __syncthreads();
    }
#pragma unroll
    for (int mi = 0; mi < 4; mi++)
#pragma unroll
        for (int ni = 0; ni < 4; ni++)
#pragma unroll
            for (int r = 0; r < 4; r++) {
                int m = m0 + wm * 64 + mi * 16 + quad * 4 + r;
                int n = n0 + wn * 64 + ni * 16 + lrow;
                C[(long)m * NG + n] = (f16)(acc[mi][ni][r] + bias[n]);
            }
}

// ---------------- phase 3: out[b][t][n] = relu(hs @ Wo + bo) (f32 out, row remap) ----------------
__launch_bounds__(256)
__global__ void gemm_hw(const f16* __restrict__ A, const f16* __restrict__ Bt,
                        const float* __restrict__ bias, float* __restrict__ out)
{
    __shared__ f16 sA[128 * 32];
    __shared__ f16 sB[128 * 32];
    const int tid = threadIdx.x;
    const int m0 = blockIdx.y * 128;
    const int n0 = blockIdx.x * 128;
    const int wave = tid >> 6, lane = tid & 63;
    const int wm = wave >> 1, wn = wave & 1;
    const int lrow = lane & 15, quad = lane >> 4;

    float4v acc[4][4];
#pragma unroll
    for (int i = 0; i < 4; i++)
#pragma unroll
        for (int j = 0; j < 4; j++) acc[i][j] = (float4v){0.f, 0.f, 0.f, 0.f};

    const int srow = tid >> 2;
    const int sk8 = (tid & 3) * 8;

    for (int k0 = 0; k0 < 512; k0 += 32) {
#pragma unroll
        for (int rr = 0; rr < 128; rr += 64) {
            const int row = rr + srow;
            *(uint4*)&sA[row * 32 + sk8] = *(const uint4*)&A[(long)(m0 + row) * 512 + k0 + sk8];
            *(uint4*)&sB[row * 32 + sk8] = *(const uint4*)&Bt[(long)(n0 + row) * 512 + k0 + sk8];
        }
        __syncthreads();
        half8 af[4], bf[4];
#pragma unroll
        for (int mi = 0; mi < 4; mi++)
            af[mi] = *(half8*)&sA[(wm * 64 + mi * 16 + lrow) * 32 + quad * 8];
#pragma unroll
        for (int ni = 0; ni < 4; ni++)
            bf[ni] = *(half8*)&sB[(wn * 64 + ni * 16 + lrow) * 32 + quad * 8];
#pragma unroll
        for (int mi = 0; mi < 4; mi++)
#pragma unroll
            for (int ni = 0; ni < 4; ni++)
                acc[mi][ni] = __builtin_amdgcn_mfma_f32_16x16x32_f16(af[mi], bf[ni], acc[mi][ni], 0, 0, 0);
        __syncthreads();
    }
#pragma unroll
    for (int mi = 0; mi < 4; mi++)
#pragma unroll
        for (int ni = 0; ni < 4; ni++)
#pragma unroll
            for (int r = 0; r < 4; r++) {
                int m = m0 + wm * 64 + mi * 16 + quad * 4 + r;   // m = t*B + b
                int n = n0 + wn * 64 + ni * 16 + lrow;
                float v = acc[mi][ni][r] + bias[n];
                v = fmaxf(v, 0.f);
                int t = m >> 5, b = m & 31;
                out[(long)b * (T_ * (long)N_) + (long)t * N_ + n] = v;
            }
}

// ---------------- phase 2: the recurrence (4 waves, all-gates-per-wave) ----------------
// 32 groups x 8 blocks x 256 threads (4 waves). Wave w owns 16 e-columns
// (e = s*64 + w*16 + lcol) for ALL 4 gates: B-frags = 4 gate-tiles x 16 K-steps
// persistent in the unified VGPR/AGPR file (256 regs; 1 wave/SIMD, which is all
// we launch). After the 64-MFMA K=512 chain each lane holds all 4 gate
// pre-acts for its column in registers -> gates fully in-register (no prelds
// LDS exchange, no second data barrier). The 4 row-replica quads split the
// transcendental work (one gate each: 2 trans instrs, +2 for tanh(c)), gathered
// by 3 shfl_xor.
// Barriers are RAW s_barrier + explicit lgkmcnt(0) only -- __syncthreads would
// drain vmcnt(0) and serialize the xpre prefetch into every step. The xpre
// prefetch runs at distance 2 (issued after the poll exits, sched_barrier-
// pinned below it so it cannot hoist above the poll's vmcnt(0) wait), giving it
// ~2 steps of slack vs ~900cy HBM latency.
// Comm protocol unchanged: tagged u64 slots, relaxed agent atomics, parity
// double-buffer. Safety: producer overwrites slot parity p (tag t+2 over tag t)
// only after its block observed tag t+1 on all its polled slots, which (via the
// two in-block raw barriers, which still order execution) requires every peer
// block to have passed the barrier following its tag-t reads.
__launch_bounds__(256, 1)
__global__ void lstm_rec(const f16* __restrict__ Ut,      // [2048 cols][512 rows] f16
                         const f16* __restrict__ xpre,    // [B][T][2048] f16
                         u64* __restrict__ hg64,          // [2][32][256] tagged h pairs
                         unsigned* __restrict__ hs32,     // [T][B][256] u32 (packed f16x2)
                         int unused)
{
    const int tid = threadIdx.x;
    const int bb = blockIdx.x & 31;   // batch
    const int s  = blockIdx.x >> 5;   // slice 0..7 (blocks of a group 32 apart -> same XCD)
    const int w    = tid >> 6;        // wave 0..3
    const int lane = tid & 63;
    const int quad = lane >> 4;       // row-replica / gate-worker id
    const int lcol = lane & 15;       // column within wave tile

    __shared__ __align__(16) unsigned hbuf32[256];   // h_{t-1}: 512 f16 packed

    // ---- persistent B-fragments: all 4 gates for this wave's 16 columns ----
    // B layout for mfma_f32_16x16x32_f16: lane holds col = lane&15,
    // k = (lane>>4)*8 + j -> 8 consecutive rows of one column = one half8.
    const int ncol = s * 64 + w * 16 + lcol;   // e-column in [0,512)
    half8 bf[4][16];
#pragma unroll
    for (int g = 0; g < 4; g++) {
        const f16* bp = Ut + ((long)(g * 512 + ncol)) * 512 + quad * 8;
#pragma unroll
        for (int ks = 0; ks < 16; ks++)
            bf[g][ks] = *(const half8*)(bp + ks * 32);
    }

    hbuf32[tid] = 0u;                 // h_{-1} = 0
    float cst = 0.f;                  // c-state of column ncol (replicated across quads)

    // xpre per-lane address: gate = quad, col = ncol
    const f16* xb = xpre + (long)bb * T_ * NG + quad * 512 + ncol;
    f16 xcA = xb[0];                  // x-preact for t=0
    f16 xcB = xb[NG];                 // x-preact for t=1
    __syncthreads();                  // prologue: full sync once is fine

    const int pslot = s * 32 + w * 8 + (lane & 7);   // producer slot (lanes 0..7)

#pragma unroll 1
    for (int t2 = 0; t2 < T_; t2 += 2) {
#pragma unroll
        for (int half = 0; half < 2; half++) {
            const int t = t2 + half;
            const f16 xuse = half ? xcB : xcA;   // x(t), loaded 2 steps ago

            // ---- C: poll h_{t-1}, then (pinned below it) prefetch x(t+2) ----
            if (t > 0) {
                const u64* slot = hg64 + (size_t)(t & 1) * 8192 + bb * 256 + tid;
                const unsigned tag = (unsigned)t;
                u64 v;
                while ((unsigned)((v = __hip_atomic_load(slot, __ATOMIC_RELAXED,
                                                         __HIP_MEMORY_SCOPE_AGENT)) >> 32) != tag) {}
                __builtin_amdgcn_sched_barrier(0);   // keep prefetch below the poll's vmcnt wait
                {
                    const long ti = (t + 2 < T_) ? (t + 2) : (T_ - 1);
                    const f16 xn = xb[ti * NG];
                    if (half) xcB = xn; else xcA = xn;
                }
                hbuf32[tid] = (unsigned)v;
            } else {
                const f16 xn = xb[2L * NG];
                xcA = xn;
                // hbuf already zeroed in prologue
            }

            // ---- D: make hbuf visible; raw barrier (no vmcnt drain) ----
            asm volatile("s_waitcnt lgkmcnt(0)" ::: "memory");
            __builtin_amdgcn_s_barrier();
            __builtin_amdgcn_sched_barrier(0);

            // ---- A: h @ U via MFMA, K=512 in-chain; A-rows = h broadcast ----
            float4v a0 = {0.f, 0.f, 0.f, 0.f}, a1 = {0.f, 0.f, 0.f, 0.f};
            float4v a2 = {0.f, 0.f, 0.f, 0.f}, a3 = {0.f, 0.f, 0.f, 0.f};
#pragma unroll
            for (int ks = 0; ks < 16; ks++) {
                U4H8 av;
                av.u = *(const uint4*)&hbuf32[ks * 16 + quad * 4];
                a0 = __builtin_amdgcn_mfma_f32_16x16x32_f16(av.h, bf[0][ks], a0, 0, 0, 0);
                a1 = __builtin_amdgcn_mfma_f32_16x16x32_f16(av.h, bf[1][ks], a1, 0, 0, 0);
                a2 = __builtin_amdgcn_mfma_f32_16x16x32_f16(av.h, bf[2][ks], a2, 0, 0, 0);
                a3 = __builtin_amdgcn_mfma_f32_16x16x32_f16(av.h, bf[3][ks], a3, 0, 0, 0);
            }

            // ---- gates, fully in-register; quad q computes gate q's trans ----
            // rows replicated -> reg0 of any lane is the column pre-act.
            float p01 = (quad == 0) ? a0[0] : a1[0];
            float p23 = (quad == 2) ? a2[0] : a3[0];
            float pre = ((quad < 2) ? p01 : p23) + (float)xuse;
            float m   = (quad == 3) ? 2.f : -1.f;      // sigmoid: exp(-x); tanh: exp(2x)
            float e   = __expf(m * pre);
            float r   = __builtin_amdgcn_rcpf(1.f + e);
            float act = (quad == 3) ? 1.f - 2.f * r : r;
            // butterfly gather of the 4 gate values (dist d: 0=act,1=b1,2=b2,3=b3)
            float b1 = __shfl_xor(act, 16);
            float b2 = __shfl_xor(act, 32);
            float b3 = __shfl_xor(b1, 32);
            float gi = (quad == 0) ? act : (quad == 1) ? b1 : (quad == 2) ? b2 : b3;
            float gf = (quad == 1) ? act : (quad == 0) ? b1 : (quad == 3) ? b2 : b3;
            float gg = (quad == 2) ? act : (quad == 3) ? b1 : (quad == 0) ? b2 : b3;
            float ct = (quad == 3) ? act : (quad == 2) ? b1 : (quad == 1) ? b2 : b3;

            cst = gf * cst + gi * ct;                  // identical in all quads
            float e2 = __expf(2.f * cst);
            float th = 1.f - 2.f * __builtin_amdgcn_rcpf(1.f + e2);
            float h  = gg * th;

            // ---- pack pairs + tagged release store (lanes 0..7 per wave) ----
            H16U cv; cv.h = (f16)h;
            unsigned hx = (unsigned)cv.s;
            unsigned lo = __shfl(hx, 2 * (lane & 7));      // col quad0 lanes
            unsigned hi = __shfl(hx, 2 * (lane & 7) + 1);
            if (lane < 8) {
                unsigned pk = lo | (hi << 16);
                u64 pv = ((u64)(unsigned)(t + 1) << 32) | (u64)pk;
                __hip_atomic_store(hg64 + (size_t)((t + 1) & 1) * 8192 + bb * 256 + pslot,
                                   pv, __ATOMIC_RELAXED, __HIP_MEMORY_SCOPE_AGENT);
                // history for gemm_hw: normal cached store (not on critical path)
                hs32[((long)t * B_ + bb) * 256 + pslot] = pk;
            }

            // ---- B: all waves done reading hbuf(t) before anyone overwrites ----
            __builtin_amdgcn_sched_barrier(0);
            __builtin_amdgcn_s_barrier();
        }
    }
}

// ---------------- launch ----------------
extern "C" void kernel_launch(void* const* d_in, const int* in_sizes, int n_in,
                              void* d_out, int out_size, void* d_ws, size_t ws_size,
                              hipStream_t stream)
{
    const float* x  = (const float*)d_in[0];
    const float* Wi = (const float*)d_in[1];
    const float* Ui = (const float*)d_in[2];
    const float* Wf = (const float*)d_in[3];
    const float* Uf = (const float*)d_in[4];
    const float* Wg = (const float*)d_in[5];
    const float* Ug = (const float*)d_in[6];
    const float* Wc = (const float*)d_in[7];
    const float* Uc = (const float*)d_in[8];
    const float* Wo = (const float*)d_in[9];
    const float* bi = (const float*)d_in[10];
    const float* bf = (const float*)d_in[11];
    const float* bg = (const float*)d_in[12];
    const float* bc = (const float*)d_in[13];
    const float* bo = (const float*)d_in[14];

    char* ws = (char*)d_ws;
    f16*      x16   = (f16*)(ws + 0L);            // 64 MB
    f16*      xpre  = (f16*)(ws + 67108864L);     // 256 MB
    f16*      hs    = (f16*)(ws + 335544320L);    // 64 MB
    f16*      wt    = (f16*)(ws + 402653184L);    // 2 MB
    f16*      ut    = (f16*)(ws + 404750336L);    // 2 MB
    f16*      wot   = (f16*)(ws + 406847488L);    // 0.5 MB
    float*    bias  = (float*)(ws + 407371776L);  // 8 KB
    u64*      hg64  = (u64*)(ws + 407379968L);    // 128 KB tagged h exchange
    // hg64 is re-poisoned to 0xAA each call -> tag 0xAAAAAAAA never matches a
    // real t in [1,2048], so stale data cannot satisfy a poll.

    prep_cast<<<dim3(32768), dim3(256), 0, stream>>>(x, x16);
    prep_w<<<dim3(1024, 10), dim3(256), 0, stream>>>(Wi, Ui, Wf, Uf, Wg, Ug, Wc, Uc, Wo,
                                                     bi, bf, bg, bc, wt, ut, wot, bias);
    gemm_xw<<<dim3(16, 512), dim3(256), 0, stream>>>(x16, wt, bias, xpre);
    lstm_rec<<<dim3(256), dim3(256), 0, stream>>>(ut, xpre, hg64, (unsigned*)hs, 0);
    gemm_hw<<<dim3(4, 512), dim3(256), 0, stream>>>(hs, wot, bo, (float*)d_out);
}